// Round 1
// baseline (2445.553 us; speedup 1.0000x reference)
//
#include <hip/hip_runtime.h>
#include <hip/hip_bf16.h>
#include <math.h>

// Problem constants (fixed by the reference)
#define NNODES 10000
#define NEDGES 320000
#define FIN    500
#define HIDN   64
#define NC     10
#define RANKP  3
#define KHOP   10
#define KP1    11   // K+1 Chebyshev terms

// ---------------------------------------------------------------------------
// MLP: x = relu(feature @ W1 + b1) @ W2 + b2   -> Tx0 (N, 10)
// 4 nodes per 256-thread block; one wave per node. W1 column reads are
// coalesced across the wave and L1/L2-resident (125 KB).
// ---------------------------------------------------------------------------
__global__ __launch_bounds__(256) void mlp_kernel(
    const float* __restrict__ feature, const float* __restrict__ W1,
    const float* __restrict__ b1, const float* __restrict__ W2,
    const float* __restrict__ b2, float* __restrict__ Tx0) {
  __shared__ float feat[4][FIN];
  __shared__ float hid[4][HIDN];
  const int t = threadIdx.x;
  const int n = t >> 6;      // wave id == local node
  const int h = t & 63;
  const int i0 = blockIdx.x * 4;

  // stage 4 feature rows, coalesced
  for (int idx = t; idx < 4 * FIN; idx += 256) {
    int nn = idx / FIN, f = idx - nn * FIN;
    feat[nn][f] = feature[(size_t)(i0 + nn) * FIN + f];
  }
  __syncthreads();

  float acc = b1[h];
#pragma unroll 4
  for (int f = 0; f < FIN; ++f)
    acc = fmaf(feat[n][f], W1[f * HIDN + h], acc);
  hid[n][h] = fmaxf(acc, 0.f);
  __syncthreads();

  if (h < NC) {
    float a2 = b2[h];
#pragma unroll
    for (int k = 0; k < HIDN; ++k)
      a2 = fmaf(hid[n][k], W2[k * NC + h], a2);
    Tx0[(size_t)(i0 + n) * NC + h] = a2;
  }
}

// ---------------------------------------------------------------------------
// Graph normalization.
// NOTE on lam: w_off[e] = -dinv[src]*w*dinv[dst] <= 0 for every edge, so
// jnp.max(w_off) <= 0 and lam = 2*max(max(w_off), 1.0) == 2.0 ALWAYS.
// Hence the 2/lam rescale is identity and diag = 2/lam - 1 = 0 — prop() has
// no diagonal term. Hardcoded (mathematical identity, not an approximation).
// ---------------------------------------------------------------------------
__global__ void deg_kernel(const int* __restrict__ src, const int* __restrict__ dst,
                           float* __restrict__ deg) {
  int e = blockIdx.x * 256 + threadIdx.x;
  if (e >= NEDGES) return;
  int s = src[e], d = dst[e];
  if (s != d) atomicAdd(&deg[s], 1.0f);
}

__global__ void dinv_kernel(float* __restrict__ deg) {  // in-place deg -> dinv
  int i = blockIdx.x * 256 + threadIdx.x;
  if (i >= NNODES) return;
  float dg = deg[i];
  deg[i] = (dg > 0.f) ? 1.0f / sqrtf(dg) : 0.f;
}

__global__ void woff_kernel(const int* __restrict__ src, const int* __restrict__ dst,
                            const float* __restrict__ dinv, float* __restrict__ w_off) {
  int e = blockIdx.x * 256 + threadIdx.x;
  if (e >= NEDGES) return;
  int s = src[e], d = dst[e];
  w_off[e] = (s != d) ? (-dinv[s] * dinv[d]) : 0.f;
}

// out = -in  (init for Tx2 = 2*prop(Tx1) - Tx0, scatter then adds 2*prop)
__global__ void negcopy_kernel(const float* __restrict__ in, float* __restrict__ out) {
  int i = blockIdx.x * 256 + threadIdx.x;
  if (i < NNODES * NC) out[i] = -in[i];
}

// tout[dst] += scale * w_off[e] * tin[src]   (10 channels)
__global__ void scatter_kernel(const int* __restrict__ src, const int* __restrict__ dst,
                               const float* __restrict__ w_off,
                               const float* __restrict__ tin, float* __restrict__ tout,
                               float scale) {
  int e = blockIdx.x * 256 + threadIdx.x;
  if (e >= NEDGES) return;
  float w = w_off[e];
  if (w == 0.f) return;
  w *= scale;
  int s = src[e], d = dst[e];
  const float* ti = tin + (size_t)s * NC;
  float* to = tout + (size_t)d * NC;
#pragma unroll
  for (int c = 0; c < NC; ++c) atomicAdd(&to[c], w * ti[c]);
}

// ---------------------------------------------------------------------------
// e_k[i] = (tanh(Tx_k[i] @ Wp[k] + bp[k]) @ gamma[:,k]) / RANK, all k at once.
// Emat layout (KP1, N) so the gemv can float4-load each e_k row.
// ---------------------------------------------------------------------------
__global__ void proj_kernel(const float* __restrict__ Txall, const float* __restrict__ Wp,
                            const float* __restrict__ bp, const float* __restrict__ gamma,
                            float* __restrict__ Emat) {
  int i = blockIdx.x * 256 + threadIdx.x;
  if (i >= NNODES) return;
  for (int k = 0; k < KP1; ++k) {
    const float* tx = Txall + ((size_t)k * NNODES + i) * NC;
    float t[NC];
#pragma unroll
    for (int c = 0; c < NC; ++c) t[c] = tx[c];
    float e = 0.f;
#pragma unroll
    for (int r = 0; r < RANKP; ++r) {
      float hh = bp[k * RANKP + r];
#pragma unroll
      for (int c = 0; c < NC; ++c)
        hh = fmaf(t[c], Wp[(k * NC + c) * RANKP + r], hh);
      e = fmaf(tanhf(hh), gamma[r * KP1 + k], e);
    }
    Emat[(size_t)k * NNODES + i] = e * (1.0f / RANKP);
  }
}

// ---------------------------------------------------------------------------
// etam(N,11) = CTC(N,N) @ E^T  — the HBM-dominant kernel (reads CTC once).
// 4 rows per block, 11 accumulators per row per thread (static indices only),
// float4 loads on both CTC (HBM) and Emat (L2-resident, 440 KB).
// ---------------------------------------------------------------------------
__global__ __launch_bounds__(256) void gemv_kernel(const float* __restrict__ CTC,
                                                   const float* __restrict__ Emat,
                                                   float* __restrict__ etam) {
  const int i0 = blockIdx.x * 4;
  const int t = threadIdx.x;
  float acc[4][KP1];
#pragma unroll
  for (int r = 0; r < 4; ++r)
#pragma unroll
    for (int k = 0; k < KP1; ++k) acc[r][k] = 0.f;

  const int n4 = NNODES / 4;  // 2500 float4 per row
  for (int j4 = t; j4 < n4; j4 += 256) {
    float4 ev[KP1];
#pragma unroll
    for (int k = 0; k < KP1; ++k)
      ev[k] = ((const float4*)(Emat + (size_t)k * NNODES))[j4];
#pragma unroll
    for (int r = 0; r < 4; ++r) {
      float4 cv = ((const float4*)(CTC + (size_t)(i0 + r) * NNODES))[j4];
#pragma unroll
      for (int k = 0; k < KP1; ++k) {
        acc[r][k] = fmaf(cv.x, ev[k].x, acc[r][k]);
        acc[r][k] = fmaf(cv.y, ev[k].y, acc[r][k]);
        acc[r][k] = fmaf(cv.z, ev[k].z, acc[r][k]);
        acc[r][k] = fmaf(cv.w, ev[k].w, acc[r][k]);
      }
    }
  }

  // wave butterfly reduce (64 lanes), then cross-wave via LDS
#pragma unroll
  for (int r = 0; r < 4; ++r)
#pragma unroll
    for (int k = 0; k < KP1; ++k) {
      float v = acc[r][k];
#pragma unroll
      for (int off = 32; off > 0; off >>= 1) v += __shfl_xor(v, off);
      acc[r][k] = v;
    }
  __shared__ float red[4][4 * KP1];
  const int w = t >> 6, lane = t & 63;
  if (lane == 0) {
#pragma unroll
    for (int r = 0; r < 4; ++r)
#pragma unroll
      for (int k = 0; k < KP1; ++k) red[w][r * KP1 + k] = acc[r][k];
  }
  __syncthreads();
  if (t < 4 * KP1) {
    float s = red[0][t] + red[1][t] + red[2][t] + red[3][t];
    int r = t / KP1, k = t - r * KP1;
    etam[(size_t)(i0 + r) * KP1 + k] = s;
  }
}

// ---------------------------------------------------------------------------
// hidden[i,c] = sum_k Tx_k[i,c] * etam[i,k]; out = log_softmax(hidden, axis=1)
// ---------------------------------------------------------------------------
__global__ void final_kernel(const float* __restrict__ Txall, const float* __restrict__ etam,
                             float* __restrict__ out) {
  int i = blockIdx.x * 256 + threadIdx.x;
  if (i >= NNODES) return;
  float eta[KP1];
#pragma unroll
  for (int k = 0; k < KP1; ++k) eta[k] = etam[(size_t)i * KP1 + k];
  float h[NC];
#pragma unroll
  for (int c = 0; c < NC; ++c) h[c] = 0.f;
  for (int k = 0; k < KP1; ++k) {
    const float* tx = Txall + ((size_t)k * NNODES + i) * NC;
#pragma unroll
    for (int c = 0; c < NC; ++c) h[c] = fmaf(tx[c], eta[k], h[c]);
  }
  float m = h[0];
#pragma unroll
  for (int c = 1; c < NC; ++c) m = fmaxf(m, h[c]);
  float s = 0.f;
#pragma unroll
  for (int c = 0; c < NC; ++c) s += expf(h[c] - m);
  float ls = logf(s);
#pragma unroll
  for (int c = 0; c < NC; ++c) out[(size_t)i * NC + c] = h[c] - m - ls;
}

// ---------------------------------------------------------------------------
extern "C" void kernel_launch(void* const* d_in, const int* in_sizes, int n_in,
                              void* d_out, int out_size, void* d_ws, size_t ws_size,
                              hipStream_t stream) {
  const float* feature = (const float*)d_in[0];
  const int*   edges   = (const int*)d_in[1];   // per harness: integer -> const int*
  const float* CTC     = (const float*)d_in[2];
  const float* W1      = (const float*)d_in[3];
  const float* b1      = (const float*)d_in[4];
  const float* W2      = (const float*)d_in[5];
  const float* b2      = (const float*)d_in[6];
  const float* gamma   = (const float*)d_in[7];
  const float* Wp      = (const float*)d_in[8];
  const float* bp      = (const float*)d_in[9];
  const int* src = edges;
  const int* dst = edges + NEDGES;
  float* out = (float*)d_out;

  // workspace carve-up (floats): total ~1.65M floats = 6.6 MB
  float* ws    = (float*)d_ws;
  float* Txall = ws;                                  // KP1 * N * NC
  float* dinv  = Txall + (size_t)KP1 * NNODES * NC;   // N   (deg -> dinv in place)
  float* w_off = dinv + NNODES;                       // E
  float* Emat  = w_off + NEDGES;                      // KP1 * N
  float* etam  = Emat + (size_t)KP1 * NNODES;         // N * KP1

  const int EB = (NEDGES + 255) / 256;
  const int NB = (NNODES + 255) / 256;
  const int XB = (NNODES * NC + 255) / 256;

  // deg must start at zero (ws is poisoned before every timed call)
  hipMemsetAsync(dinv, 0, NNODES * sizeof(float), stream);

  mlp_kernel<<<NNODES / 4, 256, 0, stream>>>(feature, W1, b1, W2, b2, Txall);
  deg_kernel<<<EB, 256, 0, stream>>>(src, dst, dinv);
  dinv_kernel<<<NB, 256, 0, stream>>>(dinv);
  woff_kernel<<<EB, 256, 0, stream>>>(src, dst, dinv, w_off);

  // Tx1 = prop(Tx0)
  float* Tx0 = Txall;
  float* Tx1 = Txall + (size_t)NNODES * NC;
  hipMemsetAsync(Tx1, 0, (size_t)NNODES * NC * sizeof(float), stream);
  scatter_kernel<<<EB, 256, 0, stream>>>(src, dst, w_off, Tx0, Tx1, 1.0f);

  // Tx_{k+1} = 2*prop(Tx_k) - Tx_{k-1}
  for (int k = 1; k < KHOP; ++k) {
    float* prev = Txall + (size_t)(k - 1) * NNODES * NC;
    float* cur  = Txall + (size_t)k * NNODES * NC;
    float* nxt  = Txall + (size_t)(k + 1) * NNODES * NC;
    negcopy_kernel<<<XB, 256, 0, stream>>>(prev, nxt);
    scatter_kernel<<<EB, 256, 0, stream>>>(src, dst, w_off, cur, nxt, 2.0f);
  }

  proj_kernel<<<NB, 256, 0, stream>>>(Txall, Wp, bp, gamma, Emat);
  gemv_kernel<<<NNODES / 4, 256, 0, stream>>>(CTC, Emat, etam);
  final_kernel<<<NB, 256, 0, stream>>>(Txall, etam, out);
}

// Round 3
// 812.440 us; speedup vs baseline: 3.0101x; 3.0101x over previous
//
#include <hip/hip_runtime.h>
#include <hip/hip_bf16.h>
#include <math.h>

// Problem constants (fixed by the reference)
#define NNODES 10000
#define NEDGES 320000
#define FIN    500
#define HIDN   64
#define NC     10
#define RANKP  3
#define KHOP   10
#define KP1    11   // K+1 Chebyshev terms

// ---------------------------------------------------------------------------
// MLP: x = relu(feature @ W1 + b1) @ W2 + b2   -> Tx0 (N, 10)
// ---------------------------------------------------------------------------
__global__ __launch_bounds__(256) void mlp_kernel(
    const float* __restrict__ feature, const float* __restrict__ W1,
    const float* __restrict__ b1, const float* __restrict__ W2,
    const float* __restrict__ b2, float* __restrict__ Tx0) {
  __shared__ float feat[4][FIN];
  __shared__ float hid[4][HIDN];
  const int t = threadIdx.x;
  const int n = t >> 6;      // wave id == local node
  const int h = t & 63;
  const int i0 = blockIdx.x * 4;

  for (int idx = t; idx < 4 * FIN; idx += 256) {
    int nn = idx / FIN, f = idx - nn * FIN;
    feat[nn][f] = feature[(size_t)(i0 + nn) * FIN + f];
  }
  __syncthreads();

  float acc = b1[h];
#pragma unroll 4
  for (int f = 0; f < FIN; ++f)
    acc = fmaf(feat[n][f], W1[f * HIDN + h], acc);
  hid[n][h] = fmaxf(acc, 0.f);
  __syncthreads();

  if (h < NC) {
    float a2 = b2[h];
#pragma unroll
    for (int k = 0; k < HIDN; ++k)
      a2 = fmaf(hid[n][k], W2[k * NC + h], a2);
    Tx0[(size_t)(i0 + n) * NC + h] = a2;
  }
}

// ---------------------------------------------------------------------------
// Graph norm. PROOF carried from R0: w_off[e] = -dinv[src]*dinv[dst] <= 0 for
// every edge, so lam = 2*max(max(w_off),1) == 2.0 always => rescale identity,
// diag == 0. prop() is a pure edge gather with weight -dinv[src]*dinv[dst].
// ---------------------------------------------------------------------------

// deg[src] += 1 (for dinv), cnt[dst] += 1 (for CSR), self-loops excluded.
__global__ void degcnt_kernel(const int* __restrict__ src, const int* __restrict__ dst,
                              float* __restrict__ deg, int* __restrict__ cnt) {
  int e = blockIdx.x * 256 + threadIdx.x;
  if (e >= NEDGES) return;
  int s = src[e], d = dst[e];
  if (s != d) {
    atomicAdd(&deg[s], 1.0f);
    atomicAdd(&cnt[d], 1);
  }
}

__global__ void dinv_kernel(float* __restrict__ deg) {  // in-place deg -> dinv
  int i = blockIdx.x * 256 + threadIdx.x;
  if (i >= NNODES) return;
  float dg = deg[i];
  deg[i] = (dg > 0.f) ? 1.0f / sqrtf(dg) : 0.f;
}

// Exclusive scan of cnt[0..N) -> row_start[0..N], plus cursor copy.
// Single block, 256 threads x 40-element chunks (two passes over cnt; L2-hot).
__global__ __launch_bounds__(256) void scan_kernel(const int* __restrict__ cnt,
                                                   int* __restrict__ row_start,
                                                   int* __restrict__ cursor) {
  const int t = threadIdx.x, lane = t & 63, w = t >> 6;
  const int CH = 40;                     // 256*40 = 10240 >= NNODES
  const int base = t * CH;
  int sum = 0;
  for (int j = 0; j < CH; ++j) {
    int idx = base + j;
    if (idx < NNODES) sum += cnt[idx];
  }
  int inc = sum;                         // wave-level inclusive scan
#pragma unroll
  for (int d = 1; d < 64; d <<= 1) {
    int u = __shfl_up(inc, d);
    if (lane >= d) inc += u;
  }
  __shared__ int wtot[4];
  if (lane == 63) wtot[w] = inc;
  __syncthreads();
  int add = 0;
  for (int i = 0; i < 4; ++i)
    if (i < w) add += wtot[i];
  int run = add + inc - sum;             // exclusive prefix for this chunk
  for (int j = 0; j < CH; ++j) {
    int idx = base + j;
    if (idx < NNODES) {
      int v = cnt[idx];
      row_start[idx] = run;
      cursor[idx] = run;
      run += v;
    }
  }
  if (t == 255) row_start[NNODES] = run; // grand total
}

// CSR fill: packed[slot] = (src, w) for each non-self edge, bucketed by dst.
__global__ void fill_kernel(const int* __restrict__ src, const int* __restrict__ dst,
                            const float* __restrict__ dinv, int* __restrict__ cursor,
                            int2* __restrict__ packed) {
  int e = blockIdx.x * 256 + threadIdx.x;
  if (e >= NEDGES) return;
  int s = src[e], d = dst[e];
  if (s == d) return;
  float w = -dinv[s] * dinv[d];
  int slot = atomicAdd(&cursor[d], 1);
  packed[slot] = make_int2(s, __float_as_int(w));
}

// ---------------------------------------------------------------------------
// Gather prop (atomic-free): one 16-lane group per node (mean in-degree = 32,
// so a full 64-lane wave per node would idle half its lanes).
//   tout[i,:] = scale * sum_{e in-edges(i)} w_e * tin[src_e,:]  - sub[i,:]
// sub == nullptr for the first prop (Tx1 = P(Tx0)); otherwise the fused
// Chebyshev step Tx2 = 2*P(Tx1) - Tx0.
// ---------------------------------------------------------------------------
__global__ __launch_bounds__(256) void gather_kernel(
    const int* __restrict__ row_start, const int2* __restrict__ packed,
    const float* __restrict__ tin, const float* __restrict__ sub,
    float* __restrict__ tout, float scale) {
  const int g    = (blockIdx.x * 256 + threadIdx.x) >> 4;  // node id (16-lane group)
  const int lane = threadIdx.x & 15;
  if (g >= NNODES) return;
  const int s0 = row_start[g], s1 = row_start[g + 1];
  float acc[NC];
#pragma unroll
  for (int c = 0; c < NC; ++c) acc[c] = 0.f;
  for (int j = s0 + lane; j < s1; j += 16) {
    int2 p = packed[j];
    float w = __int_as_float(p.y);
    const float2* t2 = (const float2*)(tin + (size_t)p.x * NC);  // rows 8B-aligned
    float2 a0 = t2[0], a1 = t2[1], a2 = t2[2], a3 = t2[3], a4 = t2[4];
    acc[0] = fmaf(w, a0.x, acc[0]); acc[1] = fmaf(w, a0.y, acc[1]);
    acc[2] = fmaf(w, a1.x, acc[2]); acc[3] = fmaf(w, a1.y, acc[3]);
    acc[4] = fmaf(w, a2.x, acc[4]); acc[5] = fmaf(w, a2.y, acc[5]);
    acc[6] = fmaf(w, a3.x, acc[6]); acc[7] = fmaf(w, a3.y, acc[7]);
    acc[8] = fmaf(w, a4.x, acc[8]); acc[9] = fmaf(w, a4.y, acc[9]);
  }
  // reduce within the 16-lane group (xor masks < 16 stay inside the group)
#pragma unroll
  for (int c = 0; c < NC; ++c) {
    float v = acc[c];
#pragma unroll
    for (int off = 8; off > 0; off >>= 1) v += __shfl_xor(v, off);
    acc[c] = v;
  }
  if (lane == 0) {
    float* to = tout + (size_t)g * NC;
    if (sub) {
      const float* sb = sub + (size_t)g * NC;
#pragma unroll
      for (int c = 0; c < NC; ++c) to[c] = fmaf(scale, acc[c], -sb[c]);
    } else {
#pragma unroll
      for (int c = 0; c < NC; ++c) to[c] = scale * acc[c];
    }
  }
}

// ---------------------------------------------------------------------------
// e_k[i] = (tanh(Tx_k[i] @ Wp[k] + bp[k]) @ gamma[:,k]) / RANK, all k at once.
// Emat layout (KP1, N) so the gemv can float4-load each e_k row.
// ---------------------------------------------------------------------------
__global__ void proj_kernel(const float* __restrict__ Txall, const float* __restrict__ Wp,
                            const float* __restrict__ bp, const float* __restrict__ gamma,
                            float* __restrict__ Emat) {
  int i = blockIdx.x * 256 + threadIdx.x;
  if (i >= NNODES) return;
  for (int k = 0; k < KP1; ++k) {
    const float* tx = Txall + ((size_t)k * NNODES + i) * NC;
    float t[NC];
#pragma unroll
    for (int c = 0; c < NC; ++c) t[c] = tx[c];
    float e = 0.f;
#pragma unroll
    for (int r = 0; r < RANKP; ++r) {
      float hh = bp[k * RANKP + r];
#pragma unroll
      for (int c = 0; c < NC; ++c)
        hh = fmaf(t[c], Wp[(k * NC + c) * RANKP + r], hh);
      e = fmaf(tanhf(hh), gamma[r * KP1 + k], e);
    }
    Emat[(size_t)k * NNODES + i] = e * (1.0f / RANKP);
  }
}

// ---------------------------------------------------------------------------
// etam(N,11) = CTC(N,N) @ E^T  — the HBM-dominant kernel (reads CTC once).
// ---------------------------------------------------------------------------
__global__ __launch_bounds__(256) void gemv_kernel(const float* __restrict__ CTC,
                                                   const float* __restrict__ Emat,
                                                   float* __restrict__ etam) {
  const int i0 = blockIdx.x * 4;
  const int t = threadIdx.x;
  float acc[4][KP1];
#pragma unroll
  for (int r = 0; r < 4; ++r)
#pragma unroll
    for (int k = 0; k < KP1; ++k) acc[r][k] = 0.f;

  const int n4 = NNODES / 4;  // 2500 float4 per row
  for (int j4 = t; j4 < n4; j4 += 256) {
    float4 ev[KP1];
#pragma unroll
    for (int k = 0; k < KP1; ++k)
      ev[k] = ((const float4*)(Emat + (size_t)k * NNODES))[j4];
#pragma unroll
    for (int r = 0; r < 4; ++r) {
      float4 cv = ((const float4*)(CTC + (size_t)(i0 + r) * NNODES))[j4];
#pragma unroll
      for (int k = 0; k < KP1; ++k) {
        acc[r][k] = fmaf(cv.x, ev[k].x, acc[r][k]);
        acc[r][k] = fmaf(cv.y, ev[k].y, acc[r][k]);
        acc[r][k] = fmaf(cv.z, ev[k].z, acc[r][k]);
        acc[r][k] = fmaf(cv.w, ev[k].w, acc[r][k]);
      }
    }
  }

#pragma unroll
  for (int r = 0; r < 4; ++r)
#pragma unroll
    for (int k = 0; k < KP1; ++k) {
      float v = acc[r][k];
#pragma unroll
      for (int off = 32; off > 0; off >>= 1) v += __shfl_xor(v, off);
      acc[r][k] = v;
    }
  __shared__ float red[4][4 * KP1];
  const int w = t >> 6, lane = t & 63;
  if (lane == 0) {
#pragma unroll
    for (int r = 0; r < 4; ++r)
#pragma unroll
      for (int k = 0; k < KP1; ++k) red[w][r * KP1 + k] = acc[r][k];
  }
  __syncthreads();
  if (t < 4 * KP1) {
    float s = red[0][t] + red[1][t] + red[2][t] + red[3][t];
    int r = t / KP1, k = t - r * KP1;
    etam[(size_t)(i0 + r) * KP1 + k] = s;
  }
}

// ---------------------------------------------------------------------------
// hidden[i,c] = sum_k Tx_k[i,c] * etam[i,k]; out = log_softmax(hidden, axis=1)
// ---------------------------------------------------------------------------
__global__ void final_kernel(const float* __restrict__ Txall, const float* __restrict__ etam,
                             float* __restrict__ out) {
  int i = blockIdx.x * 256 + threadIdx.x;
  if (i >= NNODES) return;
  float eta[KP1];
#pragma unroll
  for (int k = 0; k < KP1; ++k) eta[k] = etam[(size_t)i * KP1 + k];
  float h[NC];
#pragma unroll
  for (int c = 0; c < NC; ++c) h[c] = 0.f;
  for (int k = 0; k < KP1; ++k) {
    const float* tx = Txall + ((size_t)k * NNODES + i) * NC;
#pragma unroll
    for (int c = 0; c < NC; ++c) h[c] = fmaf(tx[c], eta[k], h[c]);
  }
  float m = h[0];
#pragma unroll
  for (int c = 1; c < NC; ++c) m = fmaxf(m, h[c]);
  float s = 0.f;
#pragma unroll
  for (int c = 0; c < NC; ++c) s += expf(h[c] - m);
  float ls = logf(s);
#pragma unroll
  for (int c = 0; c < NC; ++c) out[(size_t)i * NC + c] = h[c] - m - ls;
}

// ---------------------------------------------------------------------------
extern "C" void kernel_launch(void* const* d_in, const int* in_sizes, int n_in,
                              void* d_out, int out_size, void* d_ws, size_t ws_size,
                              hipStream_t stream) {
  const float* feature = (const float*)d_in[0];
  const int*   edges   = (const int*)d_in[1];   // verified R1: int32 works (passed)
  const float* CTC     = (const float*)d_in[2];
  const float* W1      = (const float*)d_in[3];
  const float* b1      = (const float*)d_in[4];
  const float* W2      = (const float*)d_in[5];
  const float* b2      = (const float*)d_in[6];
  const float* gamma   = (const float*)d_in[7];
  const float* Wp      = (const float*)d_in[8];
  const float* bp      = (const float*)d_in[9];
  const int* src = edges;
  const int* dst = edges + NEDGES;
  float* out = (float*)d_out;

  // workspace carve-up (~9 MB total; ws is 0xAA-poisoned before every call)
  float* ws        = (float*)d_ws;
  float* Txall     = ws;                                    // KP1 * N * NC floats
  float* deg       = Txall + (size_t)KP1 * NNODES * NC;     // N floats (deg -> dinv)
  int*   cnt       = (int*)(deg + NNODES);                  // N ints   (zeroed w/ deg)
  int*   row_start = cnt + NNODES;                          // N+1 ints
  int*   cursor    = row_start + NNODES + 8;                // N ints
  int2*  packed    = (int2*)(cursor + NNODES + 8);          // E int2 (8B-aligned)
  float* Emat      = (float*)(packed + NEDGES);             // KP1 * N floats
  float* etam      = Emat + (size_t)KP1 * NNODES;           // N * KP1 floats

  const int EB = (NEDGES + 255) / 256;
  const int NB = (NNODES + 255) / 256;
  const int GB = (NNODES * 16 + 255) / 256;   // 16-lane-group-per-node grids

  // zero deg (N floats) + cnt (N ints) in one memset — contiguous by layout
  hipMemsetAsync(deg, 0, 2 * NNODES * sizeof(float), stream);

  mlp_kernel<<<NNODES / 4, 256, 0, stream>>>(feature, W1, b1, W2, b2, Txall);
  degcnt_kernel<<<EB, 256, 0, stream>>>(src, dst, deg, cnt);
  dinv_kernel<<<NB, 256, 0, stream>>>(deg);
  scan_kernel<<<1, 256, 0, stream>>>(cnt, row_start, cursor);
  fill_kernel<<<EB, 256, 0, stream>>>(src, dst, deg, cursor, packed);

  // Tx1 = P(Tx0); then Tx_{k+1} = 2*P(Tx_k) - Tx_{k-1}  (all atomic-free)
  float* Tx0 = Txall;
  float* Tx1 = Txall + (size_t)NNODES * NC;
  gather_kernel<<<GB, 256, 0, stream>>>(row_start, packed, Tx0, nullptr, Tx1, 1.0f);
  for (int k = 1; k < KHOP; ++k) {
    float* prev = Txall + (size_t)(k - 1) * NNODES * NC;
    float* cur  = Txall + (size_t)k * NNODES * NC;
    float* nxt  = Txall + (size_t)(k + 1) * NNODES * NC;
    gather_kernel<<<GB, 256, 0, stream>>>(row_start, packed, cur, prev, nxt, 2.0f);
  }

  proj_kernel<<<NB, 256, 0, stream>>>(Txall, Wp, bp, gamma, Emat);
  gemv_kernel<<<NNODES / 4, 256, 0, stream>>>(CTC, Emat, etam);
  final_kernel<<<NB, 256, 0, stream>>>(Txall, etam, out);
}